// Round 1
// baseline (104.584 us; speedup 1.0000x reference)
//
#include <hip/hip_runtime.h>
#include <hip/hip_bf16.h>
#include <stdint.h>

typedef __bf16 bf16x8 __attribute__((ext_vector_type(8)));
typedef float f32x4 __attribute__((ext_vector_type(4)));

__device__ __forceinline__ uint16_t f32_to_bf16_rne(float f) {
    uint32_t u = __float_as_uint(f);
    u += 0x7fffu + ((u >> 16) & 1u);
    return (uint16_t)(u >> 16);
}

// Convert two fp32 arrays to bf16 (RNE) in one grid-stride kernel.
__global__ void cvt2_kernel(const float* __restrict__ a, long na4,
                            const float* __restrict__ b, long nb4,
                            uint16_t* __restrict__ oa, uint16_t* __restrict__ ob) {
    long i = (long)blockIdx.x * blockDim.x + threadIdx.x;
    const long stride = (long)gridDim.x * blockDim.x;
    const long tot = na4 + nb4;
    for (; i < tot; i += stride) {
        const float4* src; ushort4* dst; long j;
        if (i < na4) { src = (const float4*)a; dst = (ushort4*)oa; j = i; }
        else         { src = (const float4*)b; dst = (ushort4*)ob; j = i - na4; }
        float4 f = src[j];
        ushort4 o;
        o.x = f32_to_bf16_rne(f.x);
        o.y = f32_to_bf16_rne(f.y);
        o.z = f32_to_bf16_rne(f.z);
        o.w = f32_to_bf16_rne(f.w);
        dst[j] = o;
    }
}

// m97-structure bf16 GEMM: C[m][n] = sum_k A[m][k]*B[n][k] + bias[n]
// A: M x K bf16 row-major, B: N x K bf16 row-major (both K-contiguous).
// 128x128 tile, BK=32, 256 threads (4 waves, 2x2), 16x16x32 MFMA.
__global__ __launch_bounds__(256) void gemm_bf16_kernel(
    const uint16_t* __restrict__ A,
    const uint16_t* __restrict__ B,
    const float* __restrict__ bias,
    float* __restrict__ C, int M, int N, int K)
{
    __shared__ __align__(16) uint16_t Alds[128 * 32];
    __shared__ __align__(16) uint16_t Blds[128 * 32];

    const int tid  = threadIdx.x;
    const int lane = tid & 63;
    const int wave = tid >> 6;
    const int wm = wave >> 1, wn = wave & 1;

    const int MB = M >> 7;
    const int brow = blockIdx.x % MB;
    const int bcol = blockIdx.x / MB;

    // ---- staging geometry: tile is [128 rows][32 k] bf16 = 8192 B, linear in LDS.
    // Per issue, each wave writes a contiguous 1024 B chunk (lane*16 within it).
    const int off0 = wave * 1024 + lane * 16;   // issue 0: bytes [0,4096)
    const int row0 = off0 >> 6;                 // 64 B per row (32 bf16)
    const int colb = off0 & 63;                 // byte offset within row = k*2

    const uint8_t* gA0 = (const uint8_t*)A + ((size_t)(brow * 128 + row0) * K) * 2 + colb;
    const uint8_t* gA1 = gA0 + (size_t)64 * K * 2;   // issue 1: rows +64
    const uint8_t* gB0 = (const uint8_t*)B + ((size_t)(bcol * 128 + row0) * K) * 2 + colb;
    const uint8_t* gB1 = gB0 + (size_t)64 * K * 2;

    uint32_t* lA0 = (uint32_t*)((uint8_t*)Alds + off0);
    uint32_t* lA1 = (uint32_t*)((uint8_t*)Alds + off0 + 4096);
    uint32_t* lB0 = (uint32_t*)((uint8_t*)Blds + off0);
    uint32_t* lB1 = (uint32_t*)((uint8_t*)Blds + off0 + 4096);

#define STAGE() do {                                                                       \
    __builtin_amdgcn_global_load_lds((const __attribute__((address_space(1))) uint32_t*)gA0, \
                                     (__attribute__((address_space(3))) uint32_t*)lA0, 16, 0, 0); \
    __builtin_amdgcn_global_load_lds((const __attribute__((address_space(1))) uint32_t*)gA1, \
                                     (__attribute__((address_space(3))) uint32_t*)lA1, 16, 0, 0); \
    __builtin_amdgcn_global_load_lds((const __attribute__((address_space(1))) uint32_t*)gB0, \
                                     (__attribute__((address_space(3))) uint32_t*)lB0, 16, 0, 0); \
    __builtin_amdgcn_global_load_lds((const __attribute__((address_space(1))) uint32_t*)gB1, \
                                     (__attribute__((address_space(3))) uint32_t*)lB1, 16, 0, 0); \
    gA0 += 64; gA1 += 64; gB0 += 64; gB1 += 64;                                            \
} while (0)

    f32x4 acc[4][4];
#pragma unroll
    for (int mf = 0; mf < 4; ++mf)
#pragma unroll
        for (int nf = 0; nf < 4; ++nf)
            acc[mf][nf] = (f32x4){0.f, 0.f, 0.f, 0.f};

    const int nk = K >> 5;
    STAGE();

    // Fragment read geometry (16x16x32 bf16):
    // A operand: lane (m + 16 g) holds A[m][8g..8g+7]  -> ds_read_b128
    // B operand: lane (n + 16 g) holds B_kxn[8g+t][n] = W[n][8g+t] -> ds_read_b128
    const int arow = wm * 64 + (lane & 15);
    const int brw  = wn * 64 + (lane & 15);
    const int ke   = (lane >> 4) * 8;

    for (int kt = 0; kt < nk; ++kt) {
        __syncthreads();   // drains vmcnt: staged tile visible
        bf16x8 af[4], bfr[4];
#pragma unroll
        for (int mf = 0; mf < 4; ++mf)
            af[mf] = *(const bf16x8*)(&Alds[(arow + mf * 16) * 32 + ke]);
#pragma unroll
        for (int nf = 0; nf < 4; ++nf)
            bfr[nf] = *(const bf16x8*)(&Blds[(brw + nf * 16) * 32 + ke]);
        __syncthreads();   // drains lgkmcnt: regs loaded, LDS safe to overwrite
        if (kt + 1 < nk) STAGE();   // flies under the MFMAs below
#pragma unroll
        for (int mf = 0; mf < 4; ++mf)
#pragma unroll
            for (int nf = 0; nf < 4; ++nf)
                acc[mf][nf] = __builtin_amdgcn_mfma_f32_16x16x32_bf16(
                    af[mf], bfr[nf], acc[mf][nf], 0, 0, 0);
    }
#undef STAGE

    // Epilogue. D mapping (verified): col = lane&15, row = (lane>>4)*4 + t
    const int crow0 = brow * 128 + wm * 64 + (lane >> 4) * 4;
    const int ccol0 = bcol * 128 + wn * 64 + (lane & 15);
#pragma unroll
    for (int nf = 0; nf < 4; ++nf) {
        const int col = ccol0 + nf * 16;
        const float bv = bias[col];
#pragma unroll
        for (int mf = 0; mf < 4; ++mf) {
#pragma unroll
            for (int t = 0; t < 4; ++t) {
                const int row = crow0 + mf * 16 + t;
                C[(size_t)row * N + col] = acc[mf][nf][t] + bv;
            }
        }
    }
}

// Safety net for odd shapes / tiny workspace: fp32 vector GEMM, one block per row.
__global__ void gemm_fallback(const float* __restrict__ x, const float* __restrict__ w,
                              const float* __restrict__ bias, float* __restrict__ out,
                              int M, int N, int K) {
    extern __shared__ float xs[];
    const int b = blockIdx.x;
    for (int k = threadIdx.x; k < K; k += blockDim.x) xs[k] = x[(size_t)b * K + k];
    __syncthreads();
    for (int j = threadIdx.x; j < N; j += blockDim.x) {
        const float* wr = w + (size_t)j * K;
        float s = 0.f;
        for (int k = 0; k < K; ++k) s += xs[k] * wr[k];
        out[(size_t)b * N + j] = s + bias[j];
    }
}

extern "C" void kernel_launch(void* const* d_in, const int* in_sizes, int n_in,
                              void* d_out, int out_size, void* d_ws, size_t ws_size,
                              hipStream_t stream) {
    const float* x    = (const float*)d_in[0];
    const float* w    = (const float*)d_in[1];
    const float* bias = (const float*)d_in[2];
    float* out = (float*)d_out;

    const int N = in_sizes[2];
    const int K = in_sizes[1] / N;
    const int M = in_sizes[0] / K;

    const size_t need = ((size_t)M * K + (size_t)N * K) * 2;
    if ((M % 128 == 0) && (N % 128 == 0) && (K % 32 == 0) && ws_size >= need) {
        uint16_t* xb = (uint16_t*)d_ws;
        uint16_t* wb = xb + (size_t)M * K;
        const long na4 = (long)M * K / 4, nb4 = (long)N * K / 4;
        cvt2_kernel<<<2048, 256, 0, stream>>>(x, na4, w, nb4, xb, wb);
        dim3 grid((M / 128) * (N / 128));
        gemm_bf16_kernel<<<grid, 256, 0, stream>>>(xb, wb, bias, out, M, N, K);
    } else {
        gemm_fallback<<<M, 256, (size_t)K * 4, stream>>>(x, w, bias, out, M, N, K);
    }
}

// Round 2
// 97.015 us; speedup vs baseline: 1.0780x; 1.0780x over previous
//
#include <hip/hip_runtime.h>
#include <hip/hip_bf16.h>
#include <stdint.h>

typedef __bf16 bf16x8 __attribute__((ext_vector_type(8)));
typedef float f32x4 __attribute__((ext_vector_type(4)));

__device__ __forceinline__ uint16_t f32_to_bf16_rne(float f) {
    uint32_t u = __float_as_uint(f);
    u += 0x7fffu + ((u >> 16) & 1u);
    return (uint16_t)(u >> 16);
}

// Convert two fp32 arrays to bf16 (RNE) in one grid-stride kernel.
__global__ void cvt2_kernel(const float* __restrict__ a, long na4,
                            const float* __restrict__ b, long nb4,
                            uint16_t* __restrict__ oa, uint16_t* __restrict__ ob) {
    long i = (long)blockIdx.x * blockDim.x + threadIdx.x;
    const long stride = (long)gridDim.x * blockDim.x;
    const long tot = na4 + nb4;
    for (; i < tot; i += stride) {
        const float4* src; ushort4* dst; long j;
        if (i < na4) { src = (const float4*)a; dst = (ushort4*)oa; j = i; }
        else         { src = (const float4*)b; dst = (ushort4*)ob; j = i - na4; }
        float4 f = src[j];
        ushort4 o;
        o.x = f32_to_bf16_rne(f.x);
        o.y = f32_to_bf16_rne(f.y);
        o.z = f32_to_bf16_rne(f.z);
        o.w = f32_to_bf16_rne(f.w);
        dst[j] = o;
    }
}

// ---------------------------------------------------------------------------
// 8-phase-spirit GEMM: BM=128, BN=256, BK=64, 512 threads (8 waves, 2M x 4N),
// per-wave 64x64 output. Per phase (= one K-slab of 32): 8 ds_read_b128 +
// 3 global_load_lds(16B) + vmcnt(6) + barrier + 16 MFMA + barrier.
// LDS 96 KiB: A[2buf][2slab][128r][32c] + B[2buf][2slab][256r][32c], bf16,
// XOR-swizzled (off ^= (off>>3)&0x30) on both write-source and read.
// ---------------------------------------------------------------------------

#define GLD(gptr, ldsoff) __builtin_amdgcn_global_load_lds(                     \
    (const __attribute__((address_space(1))) uint32_t*)(gptr),                  \
    (__attribute__((address_space(3))) uint32_t*)(lds + (ldsoff)), 16, 0, 0)

// Stage tile slab: 1 A-unit + 2 B-units (3 vmcnt items per thread).
#define STAGE3(tk, bb, ss) do {                                                 \
    GLD(gA  + (tk) + (ss) * 32, (bb) * 16384 + (ss) * 8192 + dstA);             \
    GLD(gB0 + (tk) + (ss) * 32, 32768 + (bb) * 32768 + (ss) * 16384 + dstA);    \
    GLD(gB1 + (tk) + (ss) * 32, 32768 + (bb) * 32768 + (ss) * 16384 + 8192 + dstA); \
} while (0)

#define PHASE(bb, ss, ISSUE, VMSTR) do {                                        \
    const uint8_t* pa_ = lds + (bb) * 16384 + (ss) * 8192;                      \
    const uint8_t* pb_ = lds + 32768 + (bb) * 32768 + (ss) * 16384;             \
    bf16x8 av0 = *(const bf16x8*)(pa_ + aoff0);                                 \
    bf16x8 av1 = *(const bf16x8*)(pa_ + aoff1);                                 \
    bf16x8 av2 = *(const bf16x8*)(pa_ + aoff2);                                 \
    bf16x8 av3 = *(const bf16x8*)(pa_ + aoff3);                                 \
    bf16x8 bv0 = *(const bf16x8*)(pb_ + boff0);                                 \
    bf16x8 bv1 = *(const bf16x8*)(pb_ + boff1);                                 \
    bf16x8 bv2 = *(const bf16x8*)(pb_ + boff2);                                 \
    bf16x8 bv3 = *(const bf16x8*)(pb_ + boff3);                                 \
    ISSUE;                                                                      \
    asm volatile(VMSTR ::: "memory");                                           \
    __builtin_amdgcn_s_barrier();                                               \
    __builtin_amdgcn_s_setprio(1);                                              \
    acc[0][0] = __builtin_amdgcn_mfma_f32_16x16x32_bf16(av0, bv0, acc[0][0], 0, 0, 0); \
    acc[0][1] = __builtin_amdgcn_mfma_f32_16x16x32_bf16(av0, bv1, acc[0][1], 0, 0, 0); \
    acc[0][2] = __builtin_amdgcn_mfma_f32_16x16x32_bf16(av0, bv2, acc[0][2], 0, 0, 0); \
    acc[0][3] = __builtin_amdgcn_mfma_f32_16x16x32_bf16(av0, bv3, acc[0][3], 0, 0, 0); \
    acc[1][0] = __builtin_amdgcn_mfma_f32_16x16x32_bf16(av1, bv0, acc[1][0], 0, 0, 0); \
    acc[1][1] = __builtin_amdgcn_mfma_f32_16x16x32_bf16(av1, bv1, acc[1][1], 0, 0, 0); \
    acc[1][2] = __builtin_amdgcn_mfma_f32_16x16x32_bf16(av1, bv2, acc[1][2], 0, 0, 0); \
    acc[1][3] = __builtin_amdgcn_mfma_f32_16x16x32_bf16(av1, bv3, acc[1][3], 0, 0, 0); \
    acc[2][0] = __builtin_amdgcn_mfma_f32_16x16x32_bf16(av2, bv0, acc[2][0], 0, 0, 0); \
    acc[2][1] = __builtin_amdgcn_mfma_f32_16x16x32_bf16(av2, bv1, acc[2][1], 0, 0, 0); \
    acc[2][2] = __builtin_amdgcn_mfma_f32_16x16x32_bf16(av2, bv2, acc[2][2], 0, 0, 0); \
    acc[2][3] = __builtin_amdgcn_mfma_f32_16x16x32_bf16(av2, bv3, acc[2][3], 0, 0, 0); \
    acc[3][0] = __builtin_amdgcn_mfma_f32_16x16x32_bf16(av3, bv0, acc[3][0], 0, 0, 0); \
    acc[3][1] = __builtin_amdgcn_mfma_f32_16x16x32_bf16(av3, bv1, acc[3][1], 0, 0, 0); \
    acc[3][2] = __builtin_amdgcn_mfma_f32_16x16x32_bf16(av3, bv2, acc[3][2], 0, 0, 0); \
    acc[3][3] = __builtin_amdgcn_mfma_f32_16x16x32_bf16(av3, bv3, acc[3][3], 0, 0, 0); \
    __builtin_amdgcn_s_setprio(0);                                              \
    __builtin_amdgcn_s_barrier();                                               \
} while (0)

__global__ __launch_bounds__(512, 2) void gemm8p_bf16(
    const uint16_t* __restrict__ A,   // M x K bf16 (x)
    const uint16_t* __restrict__ B,   // N x K bf16 (weight)
    const float* __restrict__ bias,
    float* __restrict__ C, int M, int N, int K)
{
    extern __shared__ __align__(16) uint8_t lds[];
    const int tid  = threadIdx.x;
    const int lane = tid & 63;
    const int wave = tid >> 6;
    const int wr = wave >> 2;   // 0..1 (M)
    const int wc = wave & 3;    // 0..3 (N)

    // Bijective XCD-aware swizzle: 8-XCD chunks get contiguous wgids.
    const int nwg = gridDim.x;
    int swz;
    {
        const int q = nwg >> 3, r = nwg & 7;
        const int xcd = blockIdx.x & 7, k = blockIdx.x >> 3;
        swz = (xcd < r ? xcd * (q + 1) : r * (q + 1) + (xcd - r) * q) + k;
    }
    const int MB = M >> 7;
    const int brow = swz % MB;
    const int bcol = swz / MB;

    // ---- staging addressing (pre-swizzled global source, linear LDS dest)
    const int dstA = tid * 16;                                    // LDS byte off within unit
    const int csrc = ((tid & 3) ^ ((tid >> 3) & 3)) * 8;          // swizzled K-elem offset
    const uint16_t* gA  = A + (size_t)(brow * 128 +        (tid >> 2)) * K + csrc;
    const uint16_t* gB0 = B + (size_t)(bcol * 256 +        (tid >> 2)) * K + csrc;
    const uint16_t* gB1 = B + (size_t)(bcol * 256 + 128 +  (tid >> 2)) * K + csrc;

    // ---- fragment read offsets (within a slab), swizzled
    const int lm  = lane & 15;
    const int g16 = (lane >> 4) * 16;
    int aoff0, aoff1, aoff2, aoff3, boff0, boff1, boff2, boff3;
    {
        int o;
        o = (wr * 64 +  0 + lm) * 64 + g16; aoff0 = o ^ ((o >> 3) & 0x30);
        o = (wr * 64 + 16 + lm) * 64 + g16; aoff1 = o ^ ((o >> 3) & 0x30);
        o = (wr * 64 + 32 + lm) * 64 + g16; aoff2 = o ^ ((o >> 3) & 0x30);
        o = (wr * 64 + 48 + lm) * 64 + g16; aoff3 = o ^ ((o >> 3) & 0x30);
        o = (wc * 64 +  0 + lm) * 64 + g16; boff0 = o ^ ((o >> 3) & 0x30);
        o = (wc * 64 + 16 + lm) * 64 + g16; boff1 = o ^ ((o >> 3) & 0x30);
        o = (wc * 64 + 32 + lm) * 64 + g16; boff2 = o ^ ((o >> 3) & 0x30);
        o = (wc * 64 + 48 + lm) * 64 + g16; boff3 = o ^ ((o >> 3) & 0x30);
    }

    f32x4 acc[4][4];
#pragma unroll
    for (int m = 0; m < 4; ++m)
#pragma unroll
        for (int n = 0; n < 4; ++n)
            acc[m][n] = (f32x4){0.f, 0.f, 0.f, 0.f};

    const int nt = K >> 6;   // K-tiles of 64 (>= 3 guaranteed by launcher)

    // Prologue: tile0 both slabs + tile1 slab0; wait tile0-slab0 landed.
    STAGE3(0, 0, 0);
    STAGE3(0, 0, 1);
    STAGE3(64, 1, 0);
    asm volatile("s_waitcnt vmcnt(6)" ::: "memory");
    __builtin_amdgcn_s_barrier();

    int t = 0;
    for (; t <= nt - 3; ++t) {
        const int bb = t & 1;
        // phase (t,0): read slab0; issue (t+1, slab1) -> buf[t+1&1] (freed at (t-1,1))
        PHASE(bb, 0, STAGE3((t + 1) * 64, (t + 1) & 1, 1), "s_waitcnt vmcnt(6)");
        // phase (t,1): read slab1; issue (t+2, slab0) -> buf[t&1] slab0 (freed at (t,0))
        PHASE(bb, 1, STAGE3((t + 2) * 64, t & 1, 0), "s_waitcnt vmcnt(6)");
    }
    {   // t == nt-2
        const int bb = t & 1;
        PHASE(bb, 0, STAGE3((nt - 1) * 64, (nt - 1) & 1, 1), "s_waitcnt vmcnt(6)");
        PHASE(bb, 1, (void)0, "s_waitcnt vmcnt(3)");
    }
    {   // t == nt-1
        const int bb = (nt - 1) & 1;
        PHASE(bb, 0, (void)0, "s_waitcnt vmcnt(0)");
        PHASE(bb, 1, (void)0, "s_waitcnt vmcnt(0)");
    }

    // Epilogue: D mapping col = lane&15 (N), row = (lane>>4)*4 + t (M).
    const int crow0 = brow * 128 + wr * 64 + (lane >> 4) * 4;
    const int ccol0 = bcol * 256 + wc * 64 + lm;
#pragma unroll
    for (int nf = 0; nf < 4; ++nf) {
        const int col = ccol0 + nf * 16;
        const float bv = bias[col];
#pragma unroll
        for (int mf = 0; mf < 4; ++mf) {
#pragma unroll
            for (int tt = 0; tt < 4; ++tt) {
                const int row = crow0 + mf * 16 + tt;
                C[(size_t)row * N + col] = acc[mf][nf][tt] + bv;
            }
        }
    }
}

// ---------------------------------------------------------------------------
// Fallback 1: verified m97-structure 128x128 kernel (round-1 code).
// ---------------------------------------------------------------------------
__global__ __launch_bounds__(256) void gemm_bf16_kernel(
    const uint16_t* __restrict__ A,
    const uint16_t* __restrict__ B,
    const float* __restrict__ bias,
    float* __restrict__ C, int M, int N, int K)
{
    __shared__ __align__(16) uint16_t Alds[128 * 32];
    __shared__ __align__(16) uint16_t Blds[128 * 32];

    const int tid  = threadIdx.x;
    const int lane = tid & 63;
    const int wave = tid >> 6;
    const int wm = wave >> 1, wn = wave & 1;

    const int MB = M >> 7;
    const int brow = blockIdx.x % MB;
    const int bcol = blockIdx.x / MB;

    const int off0 = wave * 1024 + lane * 16;
    const int row0 = off0 >> 6;
    const int colb = off0 & 63;

    const uint8_t* gA0 = (const uint8_t*)A + ((size_t)(brow * 128 + row0) * K) * 2 + colb;
    const uint8_t* gA1 = gA0 + (size_t)64 * K * 2;
    const uint8_t* gB0 = (const uint8_t*)B + ((size_t)(bcol * 128 + row0) * K) * 2 + colb;
    const uint8_t* gB1 = gB0 + (size_t)64 * K * 2;

    uint32_t* lA0 = (uint32_t*)((uint8_t*)Alds + off0);
    uint32_t* lA1 = (uint32_t*)((uint8_t*)Alds + off0 + 4096);
    uint32_t* lB0 = (uint32_t*)((uint8_t*)Blds + off0);
    uint32_t* lB1 = (uint32_t*)((uint8_t*)Blds + off0 + 4096);

#define STAGE_OLD() do {                                                                   \
    __builtin_amdgcn_global_load_lds((const __attribute__((address_space(1))) uint32_t*)gA0, \
                                     (__attribute__((address_space(3))) uint32_t*)lA0, 16, 0, 0); \
    __builtin_amdgcn_global_load_lds((const __attribute__((address_space(1))) uint32_t*)gA1, \
                                     (__attribute__((address_space(3))) uint32_t*)lA1, 16, 0, 0); \
    __builtin_amdgcn_global_load_lds((const __attribute__((address_space(1))) uint32_t*)gB0, \
                                     (__attribute__((address_space(3))) uint32_t*)lB0, 16, 0, 0); \
    __builtin_amdgcn_global_load_lds((const __attribute__((address_space(1))) uint32_t*)gB1, \
                                     (__attribute__((address_space(3))) uint32_t*)lB1, 16, 0, 0); \
    gA0 += 64; gA1 += 64; gB0 += 64; gB1 += 64;                                            \
} while (0)

    f32x4 acc[4][4];
#pragma unroll
    for (int mf = 0; mf < 4; ++mf)
#pragma unroll
        for (int nf = 0; nf < 4; ++nf)
            acc[mf][nf] = (f32x4){0.f, 0.f, 0.f, 0.f};

    const int nk = K >> 5;
    STAGE_OLD();

    const int arow = wm * 64 + (lane & 15);
    const int brw  = wn * 64 + (lane & 15);
    const int ke   = (lane >> 4) * 8;

    for (int kt = 0; kt < nk; ++kt) {
        __syncthreads();
        bf16x8 af[4], bfr[4];
#pragma unroll
        for (int mf = 0; mf < 4; ++mf)
            af[mf] = *(const bf16x8*)(&Alds[(arow + mf * 16) * 32 + ke]);
#pragma unroll
        for (int nf = 0; nf < 4; ++nf)
            bfr[nf] = *(const bf16x8*)(&Blds[(brw + nf * 16) * 32 + ke]);
        __syncthreads();
        if (kt + 1 < nk) STAGE_OLD();
#pragma unroll
        for (int mf = 0; mf < 4; ++mf)
#pragma unroll
            for (int nf = 0; nf < 4; ++nf)
                acc[mf][nf] = __builtin_amdgcn_mfma_f32_16x16x32_bf16(
                    af[mf], bfr[nf], acc[mf][nf], 0, 0, 0);
    }
#undef STAGE_OLD

    const int crow0 = brow * 128 + wm * 64 + (lane >> 4) * 4;
    const int ccol0 = bcol * 128 + wn * 64 + (lane & 15);
#pragma unroll
    for (int nf = 0; nf < 4; ++nf) {
        const int col = ccol0 + nf * 16;
        const float bv = bias[col];
#pragma unroll
        for (int mf = 0; mf < 4; ++mf) {
#pragma unroll
            for (int t = 0; t < 4; ++t) {
                const int row = crow0 + mf * 16 + t;
                C[(size_t)row * N + col] = acc[mf][nf][t] + bv;
            }
        }
    }
}

// Fallback 2: fp32 vector GEMM, one block per row.
__global__ void gemm_fallback(const float* __restrict__ x, const float* __restrict__ w,
                              const float* __restrict__ bias, float* __restrict__ out,
                              int M, int N, int K) {
    extern __shared__ float xs[];
    const int b = blockIdx.x;
    for (int k = threadIdx.x; k < K; k += blockDim.x) xs[k] = x[(size_t)b * K + k];
    __syncthreads();
    for (int j = threadIdx.x; j < N; j += blockDim.x) {
        const float* wr = w + (size_t)j * K;
        float s = 0.f;
        for (int k = 0; k < K; ++k) s += xs[k] * wr[k];
        out[(size_t)b * N + j] = s + bias[j];
    }
}

extern "C" void kernel_launch(void* const* d_in, const int* in_sizes, int n_in,
                              void* d_out, int out_size, void* d_ws, size_t ws_size,
                              hipStream_t stream) {
    const float* x    = (const float*)d_in[0];
    const float* w    = (const float*)d_in[1];
    const float* bias = (const float*)d_in[2];
    float* out = (float*)d_out;

    const int N = in_sizes[2];
    const int K = in_sizes[1] / N;
    const int M = in_sizes[0] / K;

    const size_t need = ((size_t)M * K + (size_t)N * K) * 2;
    const bool ws_ok = ws_size >= need;

    if ((M % 128 == 0) && (N % 256 == 0) && (K % 64 == 0) && (K / 64 >= 3) && ws_ok) {
        uint16_t* xb = (uint16_t*)d_ws;
        uint16_t* wb = xb + (size_t)M * K;
        const long na4 = (long)M * K / 4, nb4 = (long)N * K / 4;
        cvt2_kernel<<<2048, 256, 0, stream>>>(x, na4, w, nb4, xb, wb);
        (void)hipFuncSetAttribute((const void*)gemm8p_bf16,
                                  hipFuncAttributeMaxDynamicSharedMemorySize, 98304);
        dim3 grid((M / 128) * (N / 256));
        gemm8p_bf16<<<grid, 512, 98304, stream>>>(xb, wb, bias, out, M, N, K);
    } else if ((M % 128 == 0) && (N % 128 == 0) && (K % 32 == 0) && ws_ok) {
        uint16_t* xb = (uint16_t*)d_ws;
        uint16_t* wb = xb + (size_t)M * K;
        const long na4 = (long)M * K / 4, nb4 = (long)N * K / 4;
        cvt2_kernel<<<2048, 256, 0, stream>>>(x, na4, w, nb4, xb, wb);
        dim3 grid((M / 128) * (N / 128));
        gemm_bf16_kernel<<<grid, 256, 0, stream>>>(xb, wb, bias, out, M, N, K);
    } else {
        gemm_fallback<<<M, 256, (size_t)K * 4, stream>>>(x, w, bias, out, M, N, K);
    }
}

// Round 3
// 94.212 us; speedup vs baseline: 1.1101x; 1.0297x over previous
//
#include <hip/hip_runtime.h>
#include <hip/hip_bf16.h>
#include <stdint.h>

typedef __bf16 bf16x8 __attribute__((ext_vector_type(8)));
typedef float f32x4 __attribute__((ext_vector_type(4)));

__device__ __forceinline__ uint16_t f32_to_bf16_rne(float f) {
    uint32_t u = __float_as_uint(f);
    u += 0x7fffu + ((u >> 16) & 1u);
    return (uint16_t)(u >> 16);
}

// Convert two fp32 arrays to bf16 (RNE) in one grid-stride kernel.
__global__ void cvt2_kernel(const float* __restrict__ a, long na4,
                            const float* __restrict__ b, long nb4,
                            uint16_t* __restrict__ oa, uint16_t* __restrict__ ob) {
    long i = (long)blockIdx.x * blockDim.x + threadIdx.x;
    const long stride = (long)gridDim.x * blockDim.x;
    const long tot = na4 + nb4;
    for (; i < tot; i += stride) {
        const float4* src; ushort4* dst; long j;
        if (i < na4) { src = (const float4*)a; dst = (ushort4*)oa; j = i; }
        else         { src = (const float4*)b; dst = (ushort4*)ob; j = i - na4; }
        float4 f = src[j];
        ushort4 o;
        o.x = f32_to_bf16_rne(f.x);
        o.y = f32_to_bf16_rne(f.y);
        o.z = f32_to_bf16_rne(f.z);
        o.w = f32_to_bf16_rne(f.w);
        dst[j] = o;
    }
}

// ---------------------------------------------------------------------------
// Pipelined GEMM: BM=128, BN=256, 8 waves (2M x 4N), per-wave 64x64 output.
// Unit of work: one K-slab of 32. Ring of 4 LDS slab regions (96 KiB):
//   region r: A at r*8192 (128x32 bf16), B at 32768 + r*16384 (256x32 bf16).
// Phase p: stage(slab p+3, 3 gload_lds) ; vmcnt(6) ; lgkmcnt(0) ; barrier ;
//          ds_read(slab p+1 -> reg[(p+1)&1]) ; setprio(1) ; 16 MFMA reg[p&1] ;
//          setprio(0).   One barrier per phase; MFMA never waits on the
//          current phase's ds_reads (register double-buffer).
// XOR swizzle (off ^= (off>>3)&0x30) on pre-swizzled global src + ds_read.
// ---------------------------------------------------------------------------

#define GLD(gptr, ldsoff) __builtin_amdgcn_global_load_lds(                     \
    (const __attribute__((address_space(1))) uint32_t*)(gptr),                  \
    (__attribute__((address_space(3))) uint32_t*)(lds + (ldsoff)), 16, 0, 0)

// Stage K-slab `s` (chunk of 32 k-elems) into ring region RS.
#define STAGE3(s, RS) do {                                                      \
    GLD(gA  + (size_t)(s) * 32, (RS) * 8192 + dstA);                            \
    GLD(gB0 + (size_t)(s) * 32, 32768 + (RS) * 16384 + dstA);                   \
    GLD(gB1 + (size_t)(s) * 32, 32768 + (RS) * 16384 + 8192 + dstA);            \
} while (0)

#define DSREAD(DA, DB, RN) do {                                                 \
    const uint8_t* pa_ = lds + (RN) * 8192;                                     \
    const uint8_t* pb_ = lds + 32768 + (RN) * 16384;                            \
    DA##0 = *(const bf16x8*)(pa_ + aoff0);                                      \
    DA##1 = *(const bf16x8*)(pa_ + aoff1);                                      \
    DA##2 = *(const bf16x8*)(pa_ + aoff2);                                      \
    DA##3 = *(const bf16x8*)(pa_ + aoff3);                                      \
    DB##0 = *(const bf16x8*)(pb_ + boff0);                                      \
    DB##1 = *(const bf16x8*)(pb_ + boff1);                                      \
    DB##2 = *(const bf16x8*)(pb_ + boff2);                                      \
    DB##3 = *(const bf16x8*)(pb_ + boff3);                                      \
} while (0)

#define MFMA16(SA, SB) do {                                                     \
    acc[0][0] = __builtin_amdgcn_mfma_f32_16x16x32_bf16(SA##0, SB##0, acc[0][0], 0, 0, 0); \
    acc[0][1] = __builtin_amdgcn_mfma_f32_16x16x32_bf16(SA##0, SB##1, acc[0][1], 0, 0, 0); \
    acc[0][2] = __builtin_amdgcn_mfma_f32_16x16x32_bf16(SA##0, SB##2, acc[0][2], 0, 0, 0); \
    acc[0][3] = __builtin_amdgcn_mfma_f32_16x16x32_bf16(SA##0, SB##3, acc[0][3], 0, 0, 0); \
    acc[1][0] = __builtin_amdgcn_mfma_f32_16x16x32_bf16(SA##1, SB##0, acc[1][0], 0, 0, 0); \
    acc[1][1] = __builtin_amdgcn_mfma_f32_16x16x32_bf16(SA##1, SB##1, acc[1][1], 0, 0, 0); \
    acc[1][2] = __builtin_amdgcn_mfma_f32_16x16x32_bf16(SA##1, SB##2, acc[1][2], 0, 0, 0); \
    acc[1][3] = __builtin_amdgcn_mfma_f32_16x16x32_bf16(SA##1, SB##3, acc[1][3], 0, 0, 0); \
    acc[2][0] = __builtin_amdgcn_mfma_f32_16x16x32_bf16(SA##2, SB##0, acc[2][0], 0, 0, 0); \
    acc[2][1] = __builtin_amdgcn_mfma_f32_16x16x32_bf16(SA##2, SB##1, acc[2][1], 0, 0, 0); \
    acc[2][2] = __builtin_amdgcn_mfma_f32_16x16x32_bf16(SA##2, SB##2, acc[2][2], 0, 0, 0); \
    acc[2][3] = __builtin_amdgcn_mfma_f32_16x16x32_bf16(SA##2, SB##3, acc[2][3], 0, 0, 0); \
    acc[3][0] = __builtin_amdgcn_mfma_f32_16x16x32_bf16(SA##3, SB##0, acc[3][0], 0, 0, 0); \
    acc[3][1] = __builtin_amdgcn_mfma_f32_16x16x32_bf16(SA##3, SB##1, acc[3][1], 0, 0, 0); \
    acc[3][2] = __builtin_amdgcn_mfma_f32_16x16x32_bf16(SA##3, SB##2, acc[3][2], 0, 0, 0); \
    acc[3][3] = __builtin_amdgcn_mfma_f32_16x16x32_bf16(SA##3, SB##3, acc[3][3], 0, 0, 0); \
} while (0)

#define PHASE(ISSUE, VMSTR, READ_STMT, SA, SB) do {                             \
    ISSUE;                                                                      \
    asm volatile(VMSTR ::: "memory");                                           \
    asm volatile("s_waitcnt lgkmcnt(0)" ::: "memory");                          \
    __builtin_amdgcn_s_barrier();                                               \
    READ_STMT;                                                                  \
    __builtin_amdgcn_s_setprio(1);                                              \
    MFMA16(SA, SB);                                                             \
    __builtin_amdgcn_s_setprio(0);                                              \
} while (0)

__global__ __launch_bounds__(512, 2) void gemm_pipe_bf16(
    const uint16_t* __restrict__ A,   // M x K bf16 (x)
    const uint16_t* __restrict__ B,   // N x K bf16 (weight)
    const float* __restrict__ bias,
    float* __restrict__ C, int M, int N, int K)
{
    extern __shared__ __align__(16) uint8_t lds[];
    const int tid  = threadIdx.x;
    const int lane = tid & 63;
    const int wave = tid >> 6;
    const int wr = wave >> 2;   // 0..1 (M)
    const int wc = wave & 3;    // 0..3 (N)

    // Bijective XCD-aware swizzle.
    const int nwg = gridDim.x;
    int swz;
    {
        const int q = nwg >> 3, r = nwg & 7;
        const int xcd = blockIdx.x & 7, k = blockIdx.x >> 3;
        swz = (xcd < r ? xcd * (q + 1) : r * (q + 1) + (xcd - r) * q) + k;
    }
    const int MB = M >> 7;
    const int brow = swz % MB;
    const int bcol = swz / MB;

    // Staging addressing (pre-swizzled global source, linear LDS dest).
    const int dstA = tid * 16;
    const int csrc = ((tid & 3) ^ ((tid >> 3) & 3)) * 8;
    const uint16_t* gA  = A + (size_t)(brow * 128 +       (tid >> 2)) * K + csrc;
    const uint16_t* gB0 = B + (size_t)(bcol * 256 +       (tid >> 2)) * K + csrc;
    const uint16_t* gB1 = B + (size_t)(bcol * 256 + 128 + (tid >> 2)) * K + csrc;

    // Fragment read offsets within a slab region, swizzled.
    const int lm  = lane & 15;
    const int g16 = (lane >> 4) * 16;
    int aoff0, aoff1, aoff2, aoff3, boff0, boff1, boff2, boff3;
    {
        int o;
        o = (wr * 64 +  0 + lm) * 64 + g16; aoff0 = o ^ ((o >> 3) & 0x30);
        o = (wr * 64 + 16 + lm) * 64 + g16; aoff1 = o ^ ((o >> 3) & 0x30);
        o = (wr * 64 + 32 + lm) * 64 + g16; aoff2 = o ^ ((o >> 3) & 0x30);
        o = (wr * 64 + 48 + lm) * 64 + g16; aoff3 = o ^ ((o >> 3) & 0x30);
        o = (wc * 64 +  0 + lm) * 64 + g16; boff0 = o ^ ((o >> 3) & 0x30);
        o = (wc * 64 + 16 + lm) * 64 + g16; boff1 = o ^ ((o >> 3) & 0x30);
        o = (wc * 64 + 32 + lm) * 64 + g16; boff2 = o ^ ((o >> 3) & 0x30);
        o = (wc * 64 + 48 + lm) * 64 + g16; boff3 = o ^ ((o >> 3) & 0x30);
    }

    f32x4 acc[4][4];
#pragma unroll
    for (int m = 0; m < 4; ++m)
#pragma unroll
        for (int n = 0; n < 4; ++n)
            acc[m][n] = (f32x4){0.f, 0.f, 0.f, 0.f};

    // Register fragment double-buffer.
    bf16x8 fa00, fa01, fa02, fa03, fb00, fb01, fb02, fb03;   // buffer 0
    bf16x8 fa10, fa11, fa12, fa13, fb10, fb11, fb12, fb13;   // buffer 1

    const int nslab = K >> 5;   // K-slabs of 32; launcher guarantees %4==0, >=8

    // Prologue: stage slabs 0,1,2 (ring 0,1,2); slab0 -> reg buffer 0.
    STAGE3(0, 0);
    STAGE3(1, 1);
    STAGE3(2, 2);
    asm volatile("s_waitcnt vmcnt(6)" ::: "memory");
    __builtin_amdgcn_s_barrier();
    DSREAD(fa0, fb0, 0);

    // Main loop: phases p .. p+3, p multiple of 4, all stage slab p+3 (vmcnt 6).
    int p = 0;
    for (; p <= nslab - 8; p += 4) {
        PHASE(STAGE3(p + 3, 3), "s_waitcnt vmcnt(6)", DSREAD(fa1, fb1, 1), fa0, fb0);
        PHASE(STAGE3(p + 4, 0), "s_waitcnt vmcnt(6)", DSREAD(fa0, fb0, 2), fa1, fb1);
        PHASE(STAGE3(p + 5, 1), "s_waitcnt vmcnt(6)", DSREAD(fa1, fb1, 3), fa0, fb0);
        PHASE(STAGE3(p + 6, 2), "s_waitcnt vmcnt(6)", DSREAD(fa0, fb0, 0), fa1, fb1);
    }
    // Tail: phases nslab-4 .. nslab-1 (p == nslab-4 here, multiple of 4).
    PHASE(STAGE3(nslab - 1, 3), "s_waitcnt vmcnt(6)", DSREAD(fa1, fb1, 1), fa0, fb0);
    PHASE((void)0,              "s_waitcnt vmcnt(3)", DSREAD(fa0, fb0, 2), fa1, fb1);
    PHASE((void)0,              "s_waitcnt vmcnt(0)", DSREAD(fa1, fb1, 3), fa0, fb0);
    PHASE((void)0,              "",                   (void)0,             fa1, fb1);

    // Epilogue: D mapping col = lane&15 (N), row = (lane>>4)*4 + t (M).
    const int crow0 = brow * 128 + wr * 64 + (lane >> 4) * 4;
    const int ccol0 = bcol * 256 + wc * 64 + lm;
#pragma unroll
    for (int nf = 0; nf < 4; ++nf) {
        const int col = ccol0 + nf * 16;
        const float bv = bias[col];
#pragma unroll
        for (int mf = 0; mf < 4; ++mf) {
#pragma unroll
            for (int tt = 0; tt < 4; ++tt) {
                const int row = crow0 + mf * 16 + tt;
                C[(size_t)row * N + col] = acc[mf][nf][tt] + bv;
            }
        }
    }
}

// ---------------------------------------------------------------------------
// Fallback 1: verified m97-structure 128x128 kernel.
// ---------------------------------------------------------------------------
__global__ __launch_bounds__(256) void gemm_bf16_kernel(
    const uint16_t* __restrict__ A,
    const uint16_t* __restrict__ B,
    const float* __restrict__ bias,
    float* __restrict__ C, int M, int N, int K)
{
    __shared__ __align__(16) uint16_t Alds[128 * 32];
    __shared__ __align__(16) uint16_t Blds[128 * 32];

    const int tid  = threadIdx.x;
    const int lane = tid & 63;
    const int wave = tid >> 6;
    const int wm = wave >> 1, wn = wave & 1;

    const int MB = M >> 7;
    const int brow = blockIdx.x % MB;
    const int bcol = blockIdx.x / MB;

    const int off0 = wave * 1024 + lane * 16;
    const int row0 = off0 >> 6;
    const int colb = off0 & 63;

    const uint8_t* gA0 = (const uint8_t*)A + ((size_t)(brow * 128 + row0) * K) * 2 + colb;
    const uint8_t* gA1 = gA0 + (size_t)64 * K * 2;
    const uint8_t* gB0 = (const uint8_t*)B + ((size_t)(bcol * 128 + row0) * K) * 2 + colb;
    const uint8_t* gB1 = gB0 + (size_t)64 * K * 2;

    uint32_t* lA0 = (uint32_t*)((uint8_t*)Alds + off0);
    uint32_t* lA1 = (uint32_t*)((uint8_t*)Alds + off0 + 4096);
    uint32_t* lB0 = (uint32_t*)((uint8_t*)Blds + off0);
    uint32_t* lB1 = (uint32_t*)((uint8_t*)Blds + off0 + 4096);

#define STAGE_OLD() do {                                                                   \
    __builtin_amdgcn_global_load_lds((const __attribute__((address_space(1))) uint32_t*)gA0, \
                                     (__attribute__((address_space(3))) uint32_t*)lA0, 16, 0, 0); \
    __builtin_amdgcn_global_load_lds((const __attribute__((address_space(1))) uint32_t*)gA1, \
                                     (__attribute__((address_space(3))) uint32_t*)lA1, 16, 0, 0); \
    __builtin_amdgcn_global_load_lds((const __attribute__((address_space(1))) uint32_t*)gB0, \
                                     (__attribute__((address_space(3))) uint32_t*)lB0, 16, 0, 0); \
    __builtin_amdgcn_global_load_lds((const __attribute__((address_space(1))) uint32_t*)gB1, \
                                     (__attribute__((address_space(3))) uint32_t*)lB1, 16, 0, 0); \
    gA0 += 64; gA1 += 64; gB0 += 64; gB1 += 64;                                            \
} while (0)

    f32x4 acc[4][4];
#pragma unroll
    for (int mf = 0; mf < 4; ++mf)
#pragma unroll
        for (int nf = 0; nf < 4; ++nf)
            acc[mf][nf] = (f32x4){0.f, 0.f, 0.f, 0.f};

    const int nk = K >> 5;
    STAGE_OLD();

    const int arow = wm * 64 + (lane & 15);
    const int brw  = wn * 64 + (lane & 15);
    const int ke   = (lane >> 4) * 8;

    for (int kt = 0; kt < nk; ++kt) {
        __syncthreads();
        bf16x8 af[4], bfr[4];
#pragma unroll
        for (int mf = 0; mf < 4; ++mf)
            af[mf] = *(const bf16x8*)(&Alds[(arow + mf * 16) * 32 + ke]);
#pragma unroll
        for (int nf = 0; nf < 4; ++nf)
            bfr[nf] = *(const bf16x8*)(&Blds[(brw + nf * 16) * 32 + ke]);
        __syncthreads();
        if (kt + 1 < nk) STAGE_OLD();
#pragma unroll
        for (int mf = 0; mf < 4; ++mf)
#pragma unroll
            for (int nf = 0; nf < 4; ++nf)
                acc[mf][nf] = __builtin_amdgcn_mfma_f32_16x16x32_bf16(
                    af[mf], bfr[nf], acc[mf][nf], 0, 0, 0);
    }
#undef STAGE_OLD

    const int crow0 = brow * 128 + wm * 64 + (lane >> 4) * 4;
    const int ccol0 = bcol * 128 + wn * 64 + (lane & 15);
#pragma unroll
    for (int nf = 0; nf < 4; ++nf) {
        const int col = ccol0 + nf * 16;
        const float bv = bias[col];
#pragma unroll
        for (int mf = 0; mf < 4; ++mf) {
#pragma unroll
            for (int t = 0; t < 4; ++t) {
                const int row = crow0 + mf * 16 + t;
                C[(size_t)row * N + col] = acc[mf][nf][t] + bv;
            }
        }
    }
}

// Fallback 2: fp32 vector GEMM, one block per row.
__global__ void gemm_fallback(const float* __restrict__ x, const float* __restrict__ w,
                              const float* __restrict__ bias, float* __restrict__ out,
                              int M, int N, int K) {
    extern __shared__ float xs[];
    const int b = blockIdx.x;
    for (int k = threadIdx.x; k < K; k += blockDim.x) xs[k] = x[(size_t)b * K + k];
    __syncthreads();
    for (int j = threadIdx.x; j < N; j += blockDim.x) {
        const float* wr = w + (size_t)j * K;
        float s = 0.f;
        for (int k = 0; k < K; ++k) s += xs[k] * wr[k];
        out[(size_t)b * N + j] = s + bias[j];
    }
}

extern "C" void kernel_launch(void* const* d_in, const int* in_sizes, int n_in,
                              void* d_out, int out_size, void* d_ws, size_t ws_size,
                              hipStream_t stream) {
    const float* x    = (const float*)d_in[0];
    const float* w    = (const float*)d_in[1];
    const float* bias = (const float*)d_in[2];
    float* out = (float*)d_out;

    const int N = in_sizes[2];
    const int K = in_sizes[1] / N;
    const int M = in_sizes[0] / K;

    const size_t need = ((size_t)M * K + (size_t)N * K) * 2;
    const bool ws_ok = ws_size >= need;

    if ((M % 128 == 0) && (N % 256 == 0) && (K % 128 == 0) && (K >= 256) && ws_ok) {
        uint16_t* xb = (uint16_t*)d_ws;
        uint16_t* wb = xb + (size_t)M * K;
        const long na4 = (long)M * K / 4, nb4 = (long)N * K / 4;
        cvt2_kernel<<<2048, 256, 0, stream>>>(x, na4, w, nb4, xb, wb);
        (void)hipFuncSetAttribute((const void*)gemm_pipe_bf16,
                                  hipFuncAttributeMaxDynamicSharedMemorySize, 98304);
        dim3 grid((M / 128) * (N / 256));
        gemm_pipe_bf16<<<grid, 512, 98304, stream>>>(xb, wb, bias, out, M, N, K);
    } else if ((M % 128 == 0) && (N % 128 == 0) && (K % 32 == 0) && ws_ok) {
        uint16_t* xb = (uint16_t*)d_ws;
        uint16_t* wb = xb + (size_t)M * K;
        const long na4 = (long)M * K / 4, nb4 = (long)N * K / 4;
        cvt2_kernel<<<2048, 256, 0, stream>>>(x, na4, w, nb4, xb, wb);
        dim3 grid((M / 128) * (N / 128));
        gemm_bf16_kernel<<<grid, 256, 0, stream>>>(xb, wb, bias, out, M, N, K);
    } else {
        gemm_fallback<<<M, 256, (size_t)K * 4, stream>>>(x, w, bias, out, M, N, K);
    }
}

// Round 4
// 86.982 us; speedup vs baseline: 1.2024x; 1.0831x over previous
//
#include <hip/hip_runtime.h>
#include <hip/hip_bf16.h>
#include <stdint.h>

typedef __bf16 bf16x8 __attribute__((ext_vector_type(8)));
typedef float f32x4 __attribute__((ext_vector_type(4)));

__device__ __forceinline__ uint16_t f32_to_bf16_rne(float f) {
    uint32_t u = __float_as_uint(f);
    u += 0x7fffu + ((u >> 16) & 1u);
    return (uint16_t)(u >> 16);
}

// Convert two fp32 arrays to bf16 (RNE) in one grid-stride kernel.
__global__ void cvt2_kernel(const float* __restrict__ a, long na4,
                            const float* __restrict__ b, long nb4,
                            uint16_t* __restrict__ oa, uint16_t* __restrict__ ob) {
    long i = (long)blockIdx.x * blockDim.x + threadIdx.x;
    const long stride = (long)gridDim.x * blockDim.x;
    const long tot = na4 + nb4;
    for (; i < tot; i += stride) {
        const float4* src; ushort4* dst; long j;
        if (i < na4) { src = (const float4*)a; dst = (ushort4*)oa; j = i; }
        else         { src = (const float4*)b; dst = (ushort4*)ob; j = i - na4; }
        float4 f = src[j];
        ushort4 o;
        o.x = f32_to_bf16_rne(f.x);
        o.y = f32_to_bf16_rne(f.y);
        o.z = f32_to_bf16_rne(f.z);
        o.w = f32_to_bf16_rne(f.w);
        dst[j] = o;
    }
}

// ---------------------------------------------------------------------------
// Phase-lagged GEMM: BM=128, BN=256, BK=64 per phase, 8 waves (2M x 4N),
// per-wave 64x64 output. Ring of 3 LDS regions x 48 KiB = 144 KiB:
//   region: A[128r][64k] bf16 (16 KiB) + B[256r][64k] (32 KiB at +16384).
// Rows are 128 B; chunk c (16 B) of row r holds global k-chunk c ^ (r&7)
// (XOR swizzle, conflict-free for both staging and fragment reads).
// Phase p: barrier; read region p -> set S(p); MFMA set S(p-1); stage
// region p+2; vmcnt(6) (covers region p+1 pre-barrier -> race-free).
// MFMA never depends on same-phase ds_reads (full phase of slack).
// ---------------------------------------------------------------------------

#define GLD(gp, lp) __builtin_amdgcn_global_load_lds(                           \
    (const __attribute__((address_space(1))) uint32_t*)(gp),                    \
    (__attribute__((address_space(3))) uint32_t*)(void*)(lp), 16, 0, 0)

// Stage one K64 region (A: 2 issues, B: 4 issues; 6 vmcnt items/wave).
#define STAGE6(KOFF, BS) do {                                                   \
    GLD(pA0 + (KOFF), (BS) + t16);                                              \
    GLD(pA1 + (KOFF), (BS) + 8192  + t16);                                      \
    GLD(pB0 + (KOFF), (BS) + 16384 + t16);                                      \
    GLD(pB1 + (KOFF), (BS) + 24576 + t16);                                      \
    GLD(pB2 + (KOFF), (BS) + 32768 + t16);                                      \
    GLD(pB3 + (KOFF), (BS) + 40960 + t16);                                      \
} while (0)

// Read 4 A-frags + 4 B-frags (one K32 half; SX=0 -> k[0,32), SX=64 -> k[32,64)).
#define READ8(P, BASE, SX) do {                                                 \
    P##a0 = *(const bf16x8*)((BASE) + (aoff0 ^ (SX)));                          \
    P##a1 = *(const bf16x8*)((BASE) + (aoff1 ^ (SX)));                          \
    P##a2 = *(const bf16x8*)((BASE) + (aoff2 ^ (SX)));                          \
    P##a3 = *(const bf16x8*)((BASE) + (aoff3 ^ (SX)));                          \
    P##b0 = *(const bf16x8*)((BASE) + (boff0 ^ (SX)));                          \
    P##b1 = *(const bf16x8*)((BASE) + (boff1 ^ (SX)));                          \
    P##b2 = *(const bf16x8*)((BASE) + (boff2 ^ (SX)));                          \
    P##b3 = *(const bf16x8*)((BASE) + (boff3 ^ (SX)));                          \
} while (0)

#define MFMA16(P) do {                                                          \
    acc[0][0] = __builtin_amdgcn_mfma_f32_16x16x32_bf16(P##a0, P##b0, acc[0][0], 0, 0, 0); \
    acc[0][1] = __builtin_amdgcn_mfma_f32_16x16x32_bf16(P##a0, P##b1, acc[0][1], 0, 0, 0); \
    acc[0][2] = __builtin_amdgcn_mfma_f32_16x16x32_bf16(P##a0, P##b2, acc[0][2], 0, 0, 0); \
    acc[0][3] = __builtin_amdgcn_mfma_f32_16x16x32_bf16(P##a0, P##b3, acc[0][3], 0, 0, 0); \
    acc[1][0] = __builtin_amdgcn_mfma_f32_16x16x32_bf16(P##a1, P##b0, acc[1][0], 0, 0, 0); \
    acc[1][1] = __builtin_amdgcn_mfma_f32_16x16x32_bf16(P##a1, P##b1, acc[1][1], 0, 0, 0); \
    acc[1][2] = __builtin_amdgcn_mfma_f32_16x16x32_bf16(P##a1, P##b2, acc[1][2], 0, 0, 0); \
    acc[1][3] = __builtin_amdgcn_mfma_f32_16x16x32_bf16(P##a1, P##b3, acc[1][3], 0, 0, 0); \
    acc[2][0] = __builtin_amdgcn_mfma_f32_16x16x32_bf16(P##a2, P##b0, acc[2][0], 0, 0, 0); \
    acc[2][1] = __builtin_amdgcn_mfma_f32_16x16x32_bf16(P##a2, P##b1, acc[2][1], 0, 0, 0); \
    acc[2][2] = __builtin_amdgcn_mfma_f32_16x16x32_bf16(P##a2, P##b2, acc[2][2], 0, 0, 0); \
    acc[2][3] = __builtin_amdgcn_mfma_f32_16x16x32_bf16(P##a2, P##b3, acc[2][3], 0, 0, 0); \
    acc[3][0] = __builtin_amdgcn_mfma_f32_16x16x32_bf16(P##a3, P##b0, acc[3][0], 0, 0, 0); \
    acc[3][1] = __builtin_amdgcn_mfma_f32_16x16x32_bf16(P##a3, P##b1, acc[3][1], 0, 0, 0); \
    acc[3][2] = __builtin_amdgcn_mfma_f32_16x16x32_bf16(P##a3, P##b2, acc[3][2], 0, 0, 0); \
    acc[3][3] = __builtin_amdgcn_mfma_f32_16x16x32_bf16(P##a3, P##b3, acc[3][3], 0, 0, 0); \
} while (0)

#define ROT3() do { uint8_t* t_ = r0; r0 = r1; r1 = r2; r2 = t_; } while (0)

// Full phase: read set R from region r0, MFMA set M (read last phase),
// stage into r2, counted vmcnt at end (covers next phase's region).
#define PHASE_FULL(R, M) do {                                                   \
    __builtin_amdgcn_s_barrier();                                               \
    __builtin_amdgcn_sched_barrier(0);                                          \
    READ8(R##x, r0, 0);                                                         \
    __builtin_amdgcn_s_setprio(1); MFMA16(M##x); __builtin_amdgcn_s_setprio(0); \
    STAGE6(kk, r2);                                                             \
    READ8(R##y, r0, 64);                                                        \
    __builtin_amdgcn_s_setprio(1); MFMA16(M##y); __builtin_amdgcn_s_setprio(0); \
    asm volatile("s_waitcnt vmcnt(6)" ::: "memory");                            \
    ROT3(); kk += 64;                                                           \
} while (0)

__global__ __launch_bounds__(512, 2) void gemm_pl_bf16(
    const uint16_t* __restrict__ A,   // M x K bf16 (x)
    const uint16_t* __restrict__ B,   // N x K bf16 (weight)
    const float* __restrict__ bias,
    float* __restrict__ C, int M, int N, int K)
{
    extern __shared__ __align__(16) uint8_t lds[];
    const int tid  = threadIdx.x;
    const int lane = tid & 63;
    const int wave = tid >> 6;
    const int wr = wave >> 2;   // 0..1 (M)
    const int wc = wave & 3;    // 0..3 (N)

    // Bijective XCD-aware swizzle.
    const int nwg = gridDim.x;
    int swz;
    {
        const int q = nwg >> 3, r = nwg & 7;
        const int xcd = blockIdx.x & 7, k = blockIdx.x >> 3;
        swz = (xcd < r ? xcd * (q + 1) : r * (q + 1) + (xcd - r) * q) + k;
    }
    const int MB = M >> 7;
    const int brow = swz % MB;
    const int bcol = swz / MB;

    // ---- staging addressing (pre-swizzled global source, linear LDS dest).
    // Chunk ci of a region sub-area: row = ci>>3, slot = ci&7; slot holds
    // global k-chunk slot ^ (row&7).
    const int t16  = tid * 16;
    const int trow = tid >> 3;                       // 0..63
    const int kc   = (tid & 7) ^ (trow & 7);         // global 16B-chunk index
    const uint16_t* pA0 = A + (size_t)(brow * 128 + trow) * K + kc * 8;
    const uint16_t* pA1 = pA0 + (size_t)64 * K;
    const uint16_t* pB0 = B + (size_t)(bcol * 256 + trow) * K + kc * 8;
    const uint16_t* pB1 = pB0 + (size_t)64 * K;
    const uint16_t* pB2 = pB0 + (size_t)128 * K;
    const uint16_t* pB3 = pB0 + (size_t)192 * K;

    // ---- fragment read offsets (region-relative), swizzled.
    // Lane (m + 16 g) of frag row-block reads global k-chunk g (s=0) at
    // slot g ^ (row&7); s=1 flips chunk bit 2 => byte XOR 64.
    const int lm   = lane & 15;
    const int g    = lane >> 4;
    const int slot = (g ^ (lm & 7)) * 16;
    const int aoff0 = (wr * 64 +  0 + lm) * 128 + slot;
    const int aoff1 = (wr * 64 + 16 + lm) * 128 + slot;
    const int aoff2 = (wr * 64 + 32 + lm) * 128 + slot;
    const int aoff3 = (wr * 64 + 48 + lm) * 128 + slot;
    const int boff0 = 16384 + (wc * 64 +  0 + lm) * 128 + slot;
    const int boff1 = 16384 + (wc * 64 + 16 + lm) * 128 + slot;
    const int boff2 = 16384 + (wc * 64 + 32 + lm) * 128 + slot;
    const int boff3 = 16384 + (wc * 64 + 48 + lm) * 128 + slot;

    f32x4 acc[4][4];
#pragma unroll
    for (int m = 0; m < 4; ++m)
#pragma unroll
        for (int n = 0; n < 4; ++n)
            acc[m][n] = (f32x4){0.f, 0.f, 0.f, 0.f};

    // Register fragment sets (E/O alternate by phase parity; x/y = K32 halves).
    bf16x8 exa0, exa1, exa2, exa3, exb0, exb1, exb2, exb3;
    bf16x8 eya0, eya1, eya2, eya3, eyb0, eyb1, eyb2, eyb3;
    bf16x8 oxa0, oxa1, oxa2, oxa3, oxb0, oxb1, oxb2, oxb3;
    bf16x8 oya0, oya1, oya2, oya3, oyb0, oyb1, oyb2, oyb3;

    const int nt = K >> 6;   // K64 phases; launcher guarantees even, >= 4
    uint8_t* r0 = lds;
    uint8_t* r1 = lds + 49152;
    uint8_t* r2 = lds + 98304;
    size_t kk = 128;         // k-element offset staged by the current phase

    // Prologue: stage regions 0,1; cover region 0.
    STAGE6(0, r0);
    STAGE6(64, r1);
    asm volatile("s_waitcnt vmcnt(6)" ::: "memory");

    // Phase 0 (reads E, no MFMA, stages region 2).
    __builtin_amdgcn_s_barrier();
    __builtin_amdgcn_sched_barrier(0);
    READ8(ex, r0, 0);
    STAGE6(kk, r2);
    READ8(ey, r0, 64);
    asm volatile("s_waitcnt vmcnt(6)" ::: "memory");
    ROT3(); kk += 64;

    // Pairs: phases 1..nt-4 (odd reads O / even reads E).
    for (int p = 1; p + 1 <= nt - 3; p += 2) {
        PHASE_FULL(o, e);
        PHASE_FULL(e, o);
    }
    // Phase nt-3 (odd): full.
    PHASE_FULL(o, e);

    // Phase nt-2 (even): no stage; drain remaining (region nt-1) pre-barrier.
    __builtin_amdgcn_s_barrier();
    __builtin_amdgcn_sched_barrier(0);
    READ8(ex, r0, 0);
    __builtin_amdgcn_s_setprio(1); MFMA16(ox); __builtin_amdgcn_s_setprio(0);
    READ8(ey, r0, 64);
    __builtin_amdgcn_s_setprio(1); MFMA16(oy); __builtin_amdgcn_s_setprio(0);
    asm volatile("s_waitcnt vmcnt(0)" ::: "memory");
    ROT3();

    // Phase nt-1 (odd): last reads.
    __builtin_amdgcn_s_barrier();
    __builtin_amdgcn_sched_barrier(0);
    READ8(ox, r0, 0);
    __builtin_amdgcn_s_setprio(1); MFMA16(ex); __builtin_amdgcn_s_setprio(0);
    READ8(oy, r0, 64);
    __builtin_amdgcn_s_setprio(1); MFMA16(ey); __builtin_amdgcn_s_setprio(0);

    // Final: consume the last-read set.
    MFMA16(ox);
    MFMA16(oy);

    // Epilogue: D mapping col = lane&15 (N), row = (lane>>4)*4 + t (M).
    const int crow0 = brow * 128 + wr * 64 + (lane >> 4) * 4;
    const int ccol0 = bcol * 256 + wc * 64 + lm;
#pragma unroll
    for (int nf = 0; nf < 4; ++nf) {
        const int col = ccol0 + nf * 16;
        const float bv = bias[col];
#pragma unroll
        for (int mf = 0; mf < 4; ++mf) {
#pragma unroll
            for (int tt = 0; tt < 4; ++tt) {
                const int row = crow0 + mf * 16 + tt;
                C[(size_t)row * N + col] = acc[mf][nf][tt] + bv;
            }
        }
    }
}

// ---------------------------------------------------------------------------
// Fallback 1: verified m97-structure 128x128 kernel.
// ---------------------------------------------------------------------------
__global__ __launch_bounds__(256) void gemm_bf16_kernel(
    const uint16_t* __restrict__ A,
    const uint16_t* __restrict__ B,
    const float* __restrict__ bias,
    float* __restrict__ C, int M, int N, int K)
{
    __shared__ __align__(16) uint16_t Alds[128 * 32];
    __shared__ __align__(16) uint16_t Blds[128 * 32];

    const int tid  = threadIdx.x;
    const int lane = tid & 63;
    const int wave = tid >> 6;
    const int wm = wave >> 1, wn = wave & 1;

    const int MB = M >> 7;
    const int brow = blockIdx.x % MB;
    const int bcol = blockIdx.x / MB;

    const int off0 = wave * 1024 + lane * 16;
    const int row0 = off0 >> 6;
    const int colb = off0 & 63;

    const uint8_t* gA0 = (const uint8_t*)A + ((size_t)(brow * 128 + row0) * K) * 2 + colb;
    const uint8_t* gA1 = gA0 + (size_t)64 * K * 2;
    const uint8_t* gB0 = (const uint8_t*)B + ((size_t)(bcol * 128 + row0) * K) * 2 + colb;
    const uint8_t* gB1 = gB0 + (size_t)64 * K * 2;

    uint32_t* lA0 = (uint32_t*)((uint8_t*)Alds + off0);
    uint32_t* lA1 = (uint32_t*)((uint8_t*)Alds + off0 + 4096);
    uint32_t* lB0 = (uint32_t*)((uint8_t*)Blds + off0);
    uint32_t* lB1 = (uint32_t*)((uint8_t*)Blds + off0 + 4096);

#define STAGE_OLD() do {                                                                   \
    __builtin_amdgcn_global_load_lds((const __attribute__((address_space(1))) uint32_t*)gA0, \
                                     (__attribute__((address_space(3))) uint32_t*)lA0, 16, 0, 0); \
    __builtin_amdgcn_global_load_lds((const __attribute__((address_space(1))) uint32_t*)gA1, \
                                     (__attribute__((address_space(3))) uint32_t*)lA1, 16, 0, 0); \
    __builtin_amdgcn_global_load_lds((const __attribute__((address_space(1))) uint32_t*)gB0, \
                                     (__attribute__((address_space(3))) uint32_t*)lB0, 16, 0, 0); \
    __builtin_amdgcn_global_load_lds((const __attribute__((address_space(1))) uint32_t*)gB1, \
                                     (__attribute__((address_space(3))) uint32_t*)lB1, 16, 0, 0); \
    gA0 += 64; gA1 += 64; gB0 += 64; gB1 += 64;                                            \
} while (0)

    f32x4 acc[4][4];
#pragma unroll
    for (int mf = 0; mf < 4; ++mf)
#pragma unroll
        for (int nf = 0; nf < 4; ++nf)
            acc[mf][nf] = (f32x4){0.f, 0.f, 0.f, 0.f};

    const int nk = K >> 5;
    STAGE_OLD();

    const int arow = wm * 64 + (lane & 15);
    const int brw  = wn * 64 + (lane & 15);
    const int ke   = (lane >> 4) * 8;

    for (int kt = 0; kt < nk; ++kt) {
        __syncthreads();
        bf16x8 af[4], bfr[4];
#pragma unroll
        for (int mf = 0; mf < 4; ++mf)
            af[mf] = *(const bf16x8*)(&Alds[(arow + mf * 16) * 32 + ke]);
#pragma unroll
        for (int nf = 0; nf < 4; ++nf)
            bfr[nf] = *(const bf16x8*)(&Blds[(brw + nf * 16) * 32 + ke]);
        __syncthreads();
        if (kt + 1 < nk) STAGE_OLD();
#pragma unroll
        for (int mf = 0; mf < 4; ++mf)
#pragma unroll
            for (int nf = 0; nf < 4; ++nf)
                acc[mf][nf] = __builtin_amdgcn_mfma_f32_16x16x32_bf16(
                    af[mf], bfr[nf], acc[mf][nf], 0, 0, 0);
    }
#undef STAGE_OLD

    const int crow0 = brow * 128 + wm * 64 + (lane >> 4) * 4;
    const int ccol0 = bcol * 128 + wn * 64 + (lane & 15);
#pragma unroll
    for (int nf = 0; nf < 4; ++nf) {
        const int col = ccol0 + nf * 16;
        const float bv = bias[col];
#pragma unroll
        for (int mf = 0; mf < 4; ++mf) {
#pragma unroll
            for (int t = 0; t < 4; ++t) {
                const int row = crow0 + mf * 16 + t;
                C[(size_t)row * N + col] = acc[mf][nf][t] + bv;
            }
        }
    }
}

// Fallback 2: fp32 vector GEMM, one block per row.
__global__ void gemm_fallback(const float* __restrict__ x, const float* __restrict__ w,
                              const float* __restrict__ bias, float* __restrict__ out,
                              int M, int N, int K) {
    extern __shared__ float xs[];
    const int b = blockIdx.x;
    for (int k = threadIdx.x; k < K; k += blockDim.x) xs[k] = x[(size_t)b * K + k];
    __syncthreads();
    for (int j = threadIdx.x; j < N; j += blockDim.x) {
        const float* wr = w + (size_t)j * K;
        float s = 0.f;
        for (int k = 0; k < K; ++k) s += xs[k] * wr[k];
        out[(size_t)b * N + j] = s + bias[j];
    }
}

extern "C" void kernel_launch(void* const* d_in, const int* in_sizes, int n_in,
                              void* d_out, int out_size, void* d_ws, size_t ws_size,
                              hipStream_t stream) {
    const float* x    = (const float*)d_in[0];
    const float* w    = (const float*)d_in[1];
    const float* bias = (const float*)d_in[2];
    float* out = (float*)d_out;

    const int N = in_sizes[2];
    const int K = in_sizes[1] / N;
    const int M = in_sizes[0] / K;

    const size_t need = ((size_t)M * K + (size_t)N * K) * 2;
    const bool ws_ok = ws_size >= need;

    if ((M % 128 == 0) && (N % 256 == 0) && (K % 128 == 0) && (K >= 256) && ws_ok) {
        uint16_t* xb = (uint16_t*)d_ws;
        uint16_t* wb = xb + (size_t)M * K;
        const long na4 = (long)M * K / 4, nb4 = (long)N * K / 4;
        cvt2_kernel<<<2048, 256, 0, stream>>>(x, na4, w, nb4, xb, wb);
        (void)hipFuncSetAttribute((const void*)gemm_pl_bf16,
                                  hipFuncAttributeMaxDynamicSharedMemorySize, 147456);
        dim3 grid((M / 128) * (N / 256));
        gemm_pl_bf16<<<grid, 512, 147456, stream>>>(xb, wb, bias, out, M, N, K);
    } else if ((M % 128 == 0) && (N % 128 == 0) && (K % 32 == 0) && ws_ok) {
        uint16_t* xb = (uint16_t*)d_ws;
        uint16_t* wb = xb + (size_t)M * K;
        const long na4 = (long)M * K / 4, nb4 = (long)N * K / 4;
        cvt2_kernel<<<2048, 256, 0, stream>>>(x, na4, w, nb4, xb, wb);
        dim3 grid((M / 128) * (N / 128));
        gemm_bf16_kernel<<<grid, 256, 0, stream>>>(xb, wb, bias, out, M, N, K);
    } else {
        gemm_fallback<<<M, 256, (size_t)K * 4, stream>>>(x, w, bias, out, M, N, K);
    }
}